// Round 1
// baseline (2236.786 us; speedup 1.0000x reference)
//
#include <hip/hip_runtime.h>
#include <stdint.h>

#define NN 2304        // nodes
#define NF 32          // frames
#define NB 1024        // batch
#define NS 256         // selected anchors

#define BM 128
#define BN 96
#define BK 64
#define KSLICES (NN / BK)   // 36
#define DEPTH 4             // async pipeline depth (slices in flight)

typedef short bf16x8 __attribute__((ext_vector_type(8)));
typedef float f32x4  __attribute__((ext_vector_type(4)));

__device__ __forceinline__ unsigned short f2bf(float f) {
  union { float f; unsigned u; } v; v.f = f;
  return (unsigned short)((v.u + 0x7FFFu + ((v.u >> 16) & 1u)) >> 16);  // RNE
}

__device__ __forceinline__ void async16(const void* g, void* l) {
  __builtin_amdgcn_global_load_lds((const __attribute__((address_space(1))) void*)g,
                                   (__attribute__((address_space(3))) void*)l, 16, 0, 0);
}

// ---------------------------------------------------------------------------
// init: convert all 31 weight matrices fp32->bf16, build keep mask, cand idx
// ---------------------------------------------------------------------------
__global__ void init_kernel(const f32x4* __restrict__ W4, const int* __restrict__ sel,
                            const int* __restrict__ cand, bf16x8* __restrict__ Wb8,
                            float* __restrict__ keep, int* __restrict__ cf,
                            int* __restrict__ cn) {
  int gid = blockIdx.x * 256 + threadIdx.x;
  if (gid < (31 * NN * NN) / 8) {
    f32x4 x = W4[2 * gid], y = W4[2 * gid + 1];
    bf16x8 o;
    o[0] = (short)f2bf(x[0]); o[1] = (short)f2bf(x[1]);
    o[2] = (short)f2bf(x[2]); o[3] = (short)f2bf(x[3]);
    o[4] = (short)f2bf(y[0]); o[5] = (short)f2bf(y[1]);
    o[6] = (short)f2bf(y[2]); o[7] = (short)f2bf(y[3]);
    Wb8[gid] = o;
  }
  if (gid < NF * NN) {
    int f = gid / NN, n = gid - f * NN;
    float v = 1.0f;
    for (int s = 0; s < NS; ++s) {
      int sf = sel[3 * s], sn = sel[3 * s + 1] * 64 + sel[3 * s + 2];
      if (sf == f && sn == n) v = 0.0f;
    }
    keep[gid] = v;
  }
  if (gid < NB) {
    cf[gid] = cand[3 * gid];
    cn[gid] = cand[3 * gid + 1] * 64 + cand[3 * gid + 2];
  }
}

// ---------------------------------------------------------------------------
// frame 0: err0 = mask(bias0), total0 = rowsum
// ---------------------------------------------------------------------------
__global__ void frame0_kernel(const float* __restrict__ bias0, const float* __restrict__ keep0,
                              const int* __restrict__ cf, const int* __restrict__ cn,
                              unsigned short* __restrict__ err, float* __restrict__ out) {
  int b = blockIdx.x, t = threadIdx.x;
  int kn = (cf[b] == 0) ? cn[b] : -1;
  float sum = 0.f;
  for (int j = t; j < NN; j += 256) {
    float v = bias0[j] * keep0[j];
    if (j == kn) v = 0.f;
    err[b * NN + j] = f2bf(v);
    sum += v;
  }
  for (int m = 32; m; m >>= 1) sum += __shfl_down(sum, m, 64);
  __shared__ float red[4];
  if ((t & 63) == 0) red[t >> 6] = sum;
  __syncthreads();
  if (t == 0) out[b] = red[0] + red[1] + red[2] + red[3];
}

// ---------------------------------------------------------------------------
// per-frame GEMM: cur = Ain(1024x2304 bf16) @ Wf^T (Wf is 2304x2304, K-major)
// epilogue: +bias, *keep, kill, write bf16 err, rowsum -> atomicAdd out
//
// v2: 512 threads (8 waves, 2/SIMD) to hide LDS/MFMA latency by TLP;
//     role-split async staging (waves 0-3: A, 4 loads; waves 4-7: B, 3 loads)
//     with role-exact vmcnt constants; depth-4 pipeline (112 KB LDS);
//     exact tail waits (fixes latent vmcnt race at s>=34);
//     XCD swizzle: one M-row of tiles per XCD (A tile + err ping-pong L2-local)
// ---------------------------------------------------------------------------
#define WAITV(n) asm volatile("s_waitcnt vmcnt(" #n ")" ::: "memory")

__launch_bounds__(512, 2)
__global__ void gemm_frame(const unsigned short* __restrict__ Ain,
                           const unsigned short* __restrict__ Wf,
                           const float* __restrict__ biasf,
                           const float* __restrict__ keepf,
                           const int* __restrict__ cf, const int* __restrict__ cn,
                           int f, unsigned short* __restrict__ errOut,
                           float* __restrict__ out) {
  __shared__ __align__(16) unsigned char sA[DEPTH][BM * BK * 2];   // 4 x 16 KB
  __shared__ __align__(16) unsigned char sB[DEPTH][BN * BK * 2];   // 4 x 12 KB

  const int t = threadIdx.x;
  const int l = t & 63, w = t >> 6;            // 8 waves
  const int wm = w >> 1, wn = w & 1;           // compute: 4x2 waves, tile 32x48 each

  // XCD swizzle: 192 blocks = 8 XCD * 24; give XCD k the full M-tile row k.
  const int id = blockIdx.x;
  const int swz = (id & 7) * 24 + (id >> 3);
  const int mBase = (swz / 24) * BM;           // M-tile 0..7
  const int nBase = (swz % 24) * BN;           // N-tile 0..23

  // staging geometry: one call = 8 rows x 64 cols (1 KB per wave);
  // lane l -> row +(l>>3), fetches swizzled chunk (l&7)^(row&7), lands at l*16
  const int sRow = l >> 3;
  const int sCk = (l & 7) ^ sRow;
  const bool aRole = (w < 4);
  const int rw = aRole ? w : (w - 4);
  const unsigned short* gSrc = aRole
      ? Ain + (mBase + rw * 32 + sRow) * NN + sCk * 8     // A: 32 rows/wave, 4 calls
      : Wf  + (nBase + rw * 24 + sRow) * NN + sCk * 8;    // B: 24 rows/wave, 3 calls

  auto issue = [&](int s, int buf) {
    const unsigned short* g = gSrc + s * BK;
    if (aRole) {
      unsigned char* la = &sA[buf][rw * 32 * 128 + l * 16];
#pragma unroll
      for (int c = 0; c < 4; ++c) async16(g + c * 8 * NN, la + c * 8 * 128);
    } else {
      unsigned char* lb = &sB[buf][rw * 24 * 128 + l * 16];
#pragma unroll
      for (int c = 0; c < 3; ++c) async16(g + c * 8 * NN, lb + c * 8 * 128);
    }
  };

  // fragment read geometry (16x16x32 bf16): lane holds [m=l&15][k=(l>>4)*8+j]
  const int fl = l & 15, q = l >> 4;
  const int fragB0 = (q ^ (fl & 7)) * 16;  // swizzled byte offset, kk=0; kk=32 -> ^64

  f32x4 acc[2][3];
#pragma unroll
  for (int r = 0; r < 2; ++r)
#pragma unroll
    for (int c = 0; c < 3; ++c) acc[r][c] = (f32x4){0.f, 0.f, 0.f, 0.f};

  issue(0, 0); issue(1, 1); issue(2, 2); issue(3, 3);

  int buf = 0;
  for (int s = 0; s < KSLICES; ++s) {
    // slice s landed when outstanding <= (slices ahead)*loads_per_slice (role-exact)
    const int ahead = KSLICES - 1 - s;           // uniform; >=3 in steady state
    if (ahead >= 3) { if (aRole) WAITV(12); else WAITV(9); }
    else if (ahead == 2) { if (aRole) WAITV(8); else WAITV(6); }
    else if (ahead == 1) { if (aRole) WAITV(4); else WAITV(3); }
    else { WAITV(0); }
    asm volatile("s_barrier" ::: "memory");

    const unsigned char* pa = &sA[buf][(wm * 32 + fl) * 128];
    const unsigned char* pb = &sB[buf][(wn * 48 + fl) * 128];
#pragma unroll
    for (int h = 0; h < 2; ++h) {
      const int cb = fragB0 ^ (h * 64);
      bf16x8 aF[2], bF[3];
#pragma unroll
      for (int r = 0; r < 2; ++r) aF[r] = *(const bf16x8*)(pa + r * 2048 + cb);
#pragma unroll
      for (int c = 0; c < 3; ++c) bF[c] = *(const bf16x8*)(pb + c * 2048 + cb);
#pragma unroll
      for (int r = 0; r < 2; ++r)
#pragma unroll
        for (int c = 0; c < 3; ++c)
          acc[r][c] = __builtin_amdgcn_mfma_f32_16x16x32_bf16(aF[r], bF[c], acc[r][c], 0, 0, 0);
    }
    // all waves done reading this buffer before DMA overwrites it
    asm volatile("s_waitcnt lgkmcnt(0)\n\ts_barrier" ::: "memory");
    if (s + DEPTH < KSLICES) issue(s + DEPTH, buf);
    buf = (buf == DEPTH - 1) ? 0 : buf + 1;
  }

  // epilogue: C/D layout col=lane&15, row=(lane>>4)*4+reg
#pragma unroll
  for (int r = 0; r < 2; ++r) {
    float rs[4] = {0.f, 0.f, 0.f, 0.f};
    const int rowB = mBase + wm * 32 + r * 16 + q * 4;
#pragma unroll
    for (int c = 0; c < 3; ++c) {
      const int col = nBase + wn * 48 + c * 16 + fl;
      const float kv = keepf[col], bv = biasf[col];
#pragma unroll
      for (int i = 0; i < 4; ++i) {
        const int row = rowB + i;
        float v = (acc[r][c][i] + bv) * kv;
        if (cf[row] == f && cn[row] == col) v = 0.f;
        errOut[row * NN + col] = f2bf(v);
        rs[i] += v;
      }
    }
#pragma unroll
    for (int m = 1; m < 16; m <<= 1) {
#pragma unroll
      for (int i = 0; i < 4; ++i) rs[i] += __shfl_xor(rs[i], m, 64);
    }
    if (fl == 0) {
#pragma unroll
      for (int i = 0; i < 4; ++i) atomicAdd(&out[rowB + i], rs[i]);
    }
  }
}

// ---------------------------------------------------------------------------
extern "C" void kernel_launch(void* const* d_in, const int* in_sizes, int n_in,
                              void* d_out, int out_size, void* d_ws, size_t ws_size,
                              hipStream_t stream) {
  (void)in_sizes; (void)n_in; (void)out_size; (void)ws_size;
  const float* W = (const float*)d_in[0];
  const float* biases = (const float*)d_in[1];
  const int* sel = (const int*)d_in[2];
  const int* cand = (const int*)d_in[3];
  float* out = (float*)d_out;
  char* ws = (char*)d_ws;

  size_t off = 0;
  unsigned short* Wb = (unsigned short*)(ws + off); off += (size_t)31 * NN * NN * 2;
  float* keep = (float*)(ws + off); off += (size_t)NF * NN * 4;
  int* cf = (int*)(ws + off); off += NB * 4;
  int* cn = (int*)(ws + off); off += NB * 4;
  off = (off + 255) & ~(size_t)255;
  unsigned short* errA = (unsigned short*)(ws + off); off += (size_t)NB * NN * 2;
  unsigned short* errB = (unsigned short*)(ws + off);

  int convBlocks = (31 * NN * NN / 8 + 255) / 256;  // 80352
  init_kernel<<<convBlocks, 256, 0, stream>>>((const f32x4*)W, sel, cand, (bf16x8*)Wb,
                                              keep, cf, cn);
  frame0_kernel<<<NB, 256, 0, stream>>>(biases, keep, cf, cn, errA, out);
  for (int f = 1; f < NF; ++f) {
    const unsigned short* Ain = (f & 1) ? errA : errB;
    unsigned short* Aout = (f & 1) ? errB : errA;
    gemm_frame<<<(NN / BN) * (NB / BM), 512, 0, stream>>>(
        Ain, Wb + (size_t)(f - 1) * NN * NN, biases + f * NN, keep + f * NN,
        cf, cn, f, Aout, out);
  }
}

// Round 2
// 1969.247 us; speedup vs baseline: 1.1359x; 1.1359x over previous
//
#include <hip/hip_runtime.h>
#include <stdint.h>

#define NN 2304        // nodes
#define NF 32          // frames
#define NB 1024        // batch
#define NS 256         // selected anchors

#define BM 128
#define BN 96
#define BK 64
#define KSLICES (NN / BK)   // 36
#define DEPTH 4             // async pipeline depth (slices in flight)
#define NGRP 8              // M-tile groups (== XCDs via id&7 swizzle)
#define GRPBLKS 24          // blocks per group (N tiles)

typedef short bf16x8 __attribute__((ext_vector_type(8)));
typedef float f32x4  __attribute__((ext_vector_type(4)));

__device__ __forceinline__ unsigned short f2bf(float f) {
  union { float f; unsigned u; } v; v.f = f;
  return (unsigned short)((v.u + 0x7FFFu + ((v.u >> 16) & 1u)) >> 16);  // RNE
}

__device__ __forceinline__ void async16(const void* g, void* l) {
  __builtin_amdgcn_global_load_lds((const __attribute__((address_space(1))) void*)g,
                                   (__attribute__((address_space(3))) void*)l, 16, 0, 0);
}

#define WAITV(n) asm volatile("s_waitcnt vmcnt(" #n ")" ::: "memory")

// ---------------------------------------------------------------------------
// init: convert all 31 weight matrices fp32->bf16, build keep mask, cand idx,
//       zero out[] (accumulated atomically now) and the group-barrier counters
// ---------------------------------------------------------------------------
__global__ void init_kernel(const f32x4* __restrict__ W4, const int* __restrict__ sel,
                            const int* __restrict__ cand, bf16x8* __restrict__ Wb8,
                            float* __restrict__ keep, int* __restrict__ cf,
                            int* __restrict__ cn, float* __restrict__ out,
                            int* __restrict__ bar) {
  int gid = blockIdx.x * 256 + threadIdx.x;
  if (gid < (31 * NN * NN) / 8) {
    f32x4 x = W4[2 * gid], y = W4[2 * gid + 1];
    bf16x8 o;
    o[0] = (short)f2bf(x[0]); o[1] = (short)f2bf(x[1]);
    o[2] = (short)f2bf(x[2]); o[3] = (short)f2bf(x[3]);
    o[4] = (short)f2bf(y[0]); o[5] = (short)f2bf(y[1]);
    o[6] = (short)f2bf(y[2]); o[7] = (short)f2bf(y[3]);
    Wb8[gid] = o;
  }
  if (gid < NF * NN) {
    int f = gid / NN, n = gid - f * NN;
    float v = 1.0f;
    for (int s = 0; s < NS; ++s) {
      int sf = sel[3 * s], sn = sel[3 * s + 1] * 64 + sel[3 * s + 2];
      if (sf == f && sn == n) v = 0.0f;
    }
    keep[gid] = v;
  }
  if (gid < NB) {
    cf[gid] = cand[3 * gid];
    cn[gid] = cand[3 * gid + 1] * 64 + cand[3 * gid + 2];
    out[gid] = 0.f;
  }
  if (gid < NGRP * NF) bar[gid] = 0;
}

// ---------------------------------------------------------------------------
// group barrier: 24 blocks sharing an M-tile row arrive+spin on one counter.
// Release: drain this block's stores (syncthreads emits vmcnt(0)) + agent
// release fence (L2 writeback) so readers on ANY XCD see the err writes.
// Acquire: agent fence (cache invalidate) before the next frame's loads.
// ---------------------------------------------------------------------------
__device__ __forceinline__ void group_barrier(int* cnt, int t) {
  __syncthreads();   // all stores of all waves drained (vmcnt 0 at barrier)
  if (t == 0) {
    __builtin_amdgcn_fence(__ATOMIC_RELEASE, "agent");
    __hip_atomic_fetch_add(cnt, 1, __ATOMIC_RELAXED, __HIP_MEMORY_SCOPE_AGENT);
    while (__hip_atomic_load(cnt, __ATOMIC_RELAXED, __HIP_MEMORY_SCOPE_AGENT) < GRPBLKS)
      __builtin_amdgcn_s_sleep(2);
    __builtin_amdgcn_fence(__ATOMIC_ACQUIRE, "agent");
  }
  __syncthreads();
}

// ---------------------------------------------------------------------------
// persistent kernel: frame0 + all 31 frame-GEMMs in one dispatch.
// Inner K-loop identical to R1 (depth-4 async, role-split staging, XOR LDS
// swizzle, role-exact vmcnt). Frames separated by the 24-block group barrier
// instead of a kernel boundary.
// ---------------------------------------------------------------------------
__launch_bounds__(512, 2)
__global__ void persist_kernel(const unsigned short* __restrict__ Wb,
                               const float* __restrict__ biases,
                               const float* __restrict__ keep,
                               const int* __restrict__ cf, const int* __restrict__ cn,
                               unsigned short* __restrict__ errA,
                               unsigned short* __restrict__ errB,
                               float* __restrict__ out, int* __restrict__ bar) {
  __shared__ __align__(16) unsigned char sA[DEPTH][BM * BK * 2];   // 4 x 16 KB
  __shared__ __align__(16) unsigned char sB[DEPTH][BN * BK * 2];   // 4 x 12 KB

  const int t = threadIdx.x;
  const int l = t & 63, w = t >> 6;            // 8 waves
  const int wm = w >> 1, wn = w & 1;           // compute: 4x2 waves, 32x48 each
  const int id = blockIdx.x;
  const int g = id & 7;                        // group == M-tile (XCD-local)
  const int mBase = g * BM;
  const int nBase = (id >> 3) * BN;

  // ---- frame 0: err0 = mask(bias0), rowsum -> atomicAdd out ----
  {
    const int row = mBase + (t >> 2);
    const int c0 = nBase + (t & 3) * 24;
    const int kn = (cf[row] == 0) ? cn[row] : -1;
    float sum = 0.f;
    for (int j = 0; j < 24; ++j) {
      const int col = c0 + j;
      float v = biases[col] * keep[col];
      if (col == kn) v = 0.f;
      errA[row * NN + col] = f2bf(v);
      sum += v;
    }
    sum += __shfl_xor(sum, 1, 64);
    sum += __shfl_xor(sum, 2, 64);
    if ((t & 3) == 0) atomicAdd(&out[row], sum);
  }
  group_barrier(&bar[g * NF + 0], t);

  // staging geometry: one issue = 8 rows x 64 cols (1 KB per wave);
  // lane l -> row +(l>>3), fetches swizzled chunk (l&7)^(row&7), lands at l*16
  const int sRow = l >> 3;
  const int sCk = (l & 7) ^ sRow;
  const bool aRole = (w < 4);
  const int rw = aRole ? w : (w - 4);
  const int ldsOff = aRole ? (rw * 32 * 128 + l * 16) : (rw * 24 * 128 + l * 16);
  const int gRowOff = aRole ? ((mBase + rw * 32 + sRow) * NN + sCk * 8)
                            : ((nBase + rw * 24 + sRow) * NN + sCk * 8);

  // fragment read geometry (16x16x32 bf16): lane holds [m=l&15][k=(l>>4)*8+j]
  const int fl = l & 15, q = l >> 4;
  const int fragB0 = (q ^ (fl & 7)) * 16;  // swizzled byte offset, kk=0; kk=32 -> ^64

  for (int f = 1; f < NF; ++f) {
    const unsigned short* Ain = (f & 1) ? errA : errB;
    unsigned short* errOut = (f & 1) ? errB : errA;
    const unsigned short* gSrc =
        (aRole ? Ain : Wb + (size_t)(f - 1) * NN * NN) + gRowOff;
    const float* biasf = biases + f * NN;
    const float* keepf = keep + f * NN;

    f32x4 acc[2][3];
#pragma unroll
    for (int r = 0; r < 2; ++r)
#pragma unroll
      for (int c = 0; c < 3; ++c) acc[r][c] = (f32x4){0.f, 0.f, 0.f, 0.f};

    // prologue: fill the pipeline
#pragma unroll
    for (int p = 0; p < DEPTH; ++p) {
      const unsigned short* gp = gSrc + p * BK;
      if (aRole) {
        unsigned char* la = &sA[p][ldsOff];
#pragma unroll
        for (int c = 0; c < 4; ++c) async16(gp + c * 8 * NN, la + c * 8 * 128);
      } else {
        unsigned char* lb = &sB[p][ldsOff];
#pragma unroll
        for (int c = 0; c < 3; ++c) async16(gp + c * 8 * NN, lb + c * 8 * 128);
      }
    }

    int buf = 0;
    for (int s = 0; s < KSLICES; ++s) {
      const int ahead = KSLICES - 1 - s;   // uniform across block
      if (ahead >= 3) { if (aRole) WAITV(12); else WAITV(9); }
      else if (ahead == 2) { if (aRole) WAITV(8); else WAITV(6); }
      else if (ahead == 1) { if (aRole) WAITV(4); else WAITV(3); }
      else { WAITV(0); }
      asm volatile("s_barrier" ::: "memory");

      const unsigned char* pa = &sA[buf][(wm * 32 + fl) * 128];
      const unsigned char* pb = &sB[buf][(wn * 48 + fl) * 128];
#pragma unroll
      for (int h = 0; h < 2; ++h) {
        const int cb = fragB0 ^ (h * 64);
        bf16x8 aF[2], bF[3];
#pragma unroll
        for (int r = 0; r < 2; ++r) aF[r] = *(const bf16x8*)(pa + r * 2048 + cb);
#pragma unroll
        for (int c = 0; c < 3; ++c) bF[c] = *(const bf16x8*)(pb + c * 2048 + cb);
#pragma unroll
        for (int r = 0; r < 2; ++r)
#pragma unroll
          for (int c = 0; c < 3; ++c)
            acc[r][c] = __builtin_amdgcn_mfma_f32_16x16x32_bf16(aF[r], bF[c], acc[r][c], 0, 0, 0);
      }
      // all waves done reading this buffer before DMA overwrites it
      asm volatile("s_waitcnt lgkmcnt(0)\n\ts_barrier" ::: "memory");
      if (s + DEPTH < KSLICES) {
        const unsigned short* gp = gSrc + (s + DEPTH) * BK;
        if (aRole) {
          unsigned char* la = &sA[buf][ldsOff];
#pragma unroll
          for (int c = 0; c < 4; ++c) async16(gp + c * 8 * NN, la + c * 8 * 128);
        } else {
          unsigned char* lb = &sB[buf][ldsOff];
#pragma unroll
          for (int c = 0; c < 3; ++c) async16(gp + c * 8 * NN, lb + c * 8 * 128);
        }
      }
      buf = (buf == DEPTH - 1) ? 0 : buf + 1;
    }

    // epilogue: C/D layout col=lane&15, row=(lane>>4)*4+reg
#pragma unroll
    for (int r = 0; r < 2; ++r) {
      float rs[4] = {0.f, 0.f, 0.f, 0.f};
      const int rowB = mBase + wm * 32 + r * 16 + q * 4;
#pragma unroll
      for (int c = 0; c < 3; ++c) {
        const int col = nBase + wn * 48 + c * 16 + fl;
        const float kv = keepf[col], bv = biasf[col];
#pragma unroll
        for (int i = 0; i < 4; ++i) {
          const int row = rowB + i;
          float v = (acc[r][c][i] + bv) * kv;
          if (cf[row] == f && cn[row] == col) v = 0.f;
          errOut[row * NN + col] = f2bf(v);
          rs[i] += v;
        }
      }
#pragma unroll
      for (int m = 1; m < 16; m <<= 1) {
#pragma unroll
        for (int i = 0; i < 4; ++i) rs[i] += __shfl_xor(rs[i], m, 64);
      }
      if (fl == 0) {
#pragma unroll
        for (int i = 0; i < 4; ++i) atomicAdd(&out[rowB + i], rs[i]);
      }
    }

    group_barrier(&bar[g * NF + f], t);
  }
}

// ---------------------------------------------------------------------------
extern "C" void kernel_launch(void* const* d_in, const int* in_sizes, int n_in,
                              void* d_out, int out_size, void* d_ws, size_t ws_size,
                              hipStream_t stream) {
  (void)in_sizes; (void)n_in; (void)out_size; (void)ws_size;
  const float* W = (const float*)d_in[0];
  const float* biases = (const float*)d_in[1];
  const int* sel = (const int*)d_in[2];
  const int* cand = (const int*)d_in[3];
  float* out = (float*)d_out;
  char* ws = (char*)d_ws;

  size_t off = 0;
  unsigned short* Wb = (unsigned short*)(ws + off); off += (size_t)31 * NN * NN * 2;
  float* keep = (float*)(ws + off); off += (size_t)NF * NN * 4;
  int* cf = (int*)(ws + off); off += NB * 4;
  int* cn = (int*)(ws + off); off += NB * 4;
  int* bar = (int*)(ws + off); off += NGRP * NF * 4;
  off = (off + 255) & ~(size_t)255;
  unsigned short* errA = (unsigned short*)(ws + off); off += (size_t)NB * NN * 2;
  unsigned short* errB = (unsigned short*)(ws + off);

  int convBlocks = (31 * NN * NN / 8 + 255) / 256;  // 80352
  init_kernel<<<convBlocks, 256, 0, stream>>>((const f32x4*)W, sel, cand, (bf16x8*)Wb,
                                              keep, cf, cn, out, bar);

  const unsigned short* WbC = Wb;
  void* kargs[] = {(void*)&WbC, (void*)&biases, (void*)&keep, (void*)&cf, (void*)&cn,
                   (void*)&errA, (void*)&errB, (void*)&out, (void*)&bar};
  hipError_t e = hipLaunchCooperativeKernel(
      reinterpret_cast<void*>(persist_kernel), dim3(NGRP * GRPBLKS), dim3(512),
      kargs, 0, stream);
  if (e != hipSuccess) {
    // graph-capture fallback: 192 blocks at 1 block/CU on 256 CUs are
    // physically co-resident; group barrier only spans 24 blocks.
    persist_kernel<<<NGRP * GRPBLKS, 512, 0, stream>>>(Wb, biases, keep, cf, cn,
                                                       errA, errB, out, bar);
  }
}